// Round 2
// baseline (284.941 us; speedup 1.0000x reference)
//
#include <hip/hip_runtime.h>
#include <hip/hip_bf16.h>
#include <math.h>

// ---- constants for this problem ----
#define BATCH 4
#define SEQ   2048
#define DM    1024
#define NHEAD 16
#define HDIM  64
#define MROWS (BATCH*SEQ)   // 8192

typedef float f32x4 __attribute__((ext_vector_type(4)));
typedef short bf16x8 __attribute__((ext_vector_type(8)));  // 8 bf16 in 4 VGPRs

typedef __attribute__((address_space(1))) unsigned int as1_u32;
typedef __attribute__((address_space(3))) unsigned int as3_u32;

__device__ __forceinline__ void gld16(const void* g, void* l) {
    // async global->LDS, 16B per lane; LDS dest = wave-uniform base + lane*16
    __builtin_amdgcn_global_load_lds((const as1_u32*)g, (as3_u32*)l, 16, 0, 0);
}

__device__ __forceinline__ unsigned short f2bf(float f) {
    unsigned int u = __float_as_uint(f);
    u += 0x7FFFu + ((u >> 16) & 1u);   // RNE
    return (unsigned short)(u >> 16);
}

// ---------------- convert X (fp32 -> bf16, same layout) ----------------
__global__ __launch_bounds__(256) void convx_kernel(const float* __restrict__ in,
                                                    unsigned short* __restrict__ out,
                                                    int n8) {
    int i = blockIdx.x * 256 + threadIdx.x;
    if (i >= n8) return;
    const float4* p = reinterpret_cast<const float4*>(in) + (size_t)i * 2;
    float4 a = p[0], b = p[1];
    uint4 r;
    r.x = (unsigned int)f2bf(a.x) | ((unsigned int)f2bf(a.y) << 16);
    r.y = (unsigned int)f2bf(a.z) | ((unsigned int)f2bf(a.w) << 16);
    r.z = (unsigned int)f2bf(b.x) | ((unsigned int)f2bf(b.y) << 16);
    r.w = (unsigned int)f2bf(b.z) | ((unsigned int)f2bf(b.w) << 16);
    reinterpret_cast<uint4*>(out)[i] = r;
}

// ---------------- convert + transpose W: [K][N] f32 -> [N][K] bf16, *scale ----------------
__global__ __launch_bounds__(256) void convw_kernel(const float* __restrict__ in,
                                                    unsigned short* __restrict__ out,
                                                    float scale) {
    __shared__ float tile[64][65];
    int n0 = blockIdx.x * 64, k0 = blockIdx.y * 64;
    int tx = threadIdx.x, ty = threadIdx.y;  // (64,4)
#pragma unroll
    for (int i = 0; i < 64; i += 4)
        tile[ty + i][tx] = in[(size_t)(k0 + ty + i) * DM + n0 + tx];
    __syncthreads();
#pragma unroll
    for (int i = 0; i < 64; i += 4)
        out[(size_t)(n0 + ty + i) * DM + k0 + tx] = f2bf(tile[tx][ty + i] * scale);
}

// ---------------- GEMM: C[M=8192,N=1024] = A[M,K=1024](bf16) @ Bt[N,K](bf16)^T ----------------
// writes bf16 out in [B,H,S,D] layout
__global__ __launch_bounds__(256) void gemm128_kernel(const unsigned short* __restrict__ A,
                                                      const unsigned short* __restrict__ Bt,
                                                      unsigned short* __restrict__ out) {
    __shared__ unsigned short lA[128 * 32];
    __shared__ unsigned short lB[128 * 32];
    const int tid = threadIdx.x, lane = tid & 63, wave = tid >> 6;
    const int m0 = blockIdx.y << 7, n0 = blockIdx.x << 7;
    const int wr = wave >> 1, wc = wave & 1;
    const int col = lane & 15, grp = lane >> 4;

    f32x4 acc[4][4] = {};

    const int srow = tid >> 2, sseg = tid & 3;
    const unsigned short* srcA0 = A + (size_t)(m0 + srow) * DM + sseg * 8;
    const unsigned short* srcA1 = srcA0 + (size_t)64 * DM;
    const unsigned short* srcB0 = Bt + (size_t)(n0 + srow) * DM + sseg * 8;
    const unsigned short* srcB1 = srcB0 + (size_t)64 * DM;
    // wave-uniform LDS staging bases (bytes): wave*1024 ; shot1 at +4096
    unsigned short* dA0 = &lA[wave * 512];
    unsigned short* dA1 = &lA[2048 + wave * 512];
    unsigned short* dB0 = &lB[wave * 512];
    unsigned short* dB1 = &lB[2048 + wave * 512];

    for (int k0 = 0; k0 < DM; k0 += 32) {
        __syncthreads();  // protect LDS from previous iteration's readers
        gld16(srcA0 + k0, dA0);
        gld16(srcA1 + k0, dA1);
        gld16(srcB0 + k0, dB0);
        gld16(srcB1 + k0, dB1);
        __syncthreads();  // compiler drains vmcnt(0) before barrier -> staging visible

        bf16x8 af[4], bfr[4];
#pragma unroll
        for (int mt = 0; mt < 4; mt++)
            af[mt] = *reinterpret_cast<const bf16x8*>(&lA[(wr * 64 + mt * 16 + col) * 32 + grp * 8]);
#pragma unroll
        for (int nt = 0; nt < 4; nt++)
            bfr[nt] = *reinterpret_cast<const bf16x8*>(&lB[(wc * 64 + nt * 16 + col) * 32 + grp * 8]);
#pragma unroll
        for (int mt = 0; mt < 4; mt++)
#pragma unroll
            for (int nt = 0; nt < 4; nt++)
                acc[mt][nt] = __builtin_amdgcn_mfma_f32_16x16x32_bf16(af[mt], bfr[nt], acc[mt][nt], 0, 0, 0);
    }

    // epilogue: C row m=(b,s), col n=(h,d) -> out[b][h][s][d] bf16
#pragma unroll
    for (int mt = 0; mt < 4; mt++) {
        int rowb = m0 + wr * 64 + mt * 16 + grp * 4;
#pragma unroll
        for (int nt = 0; nt < 4; nt++) {
            int c = n0 + wc * 64 + nt * 16 + col;
            int h = c >> 6, d = c & 63;
#pragma unroll
            for (int r = 0; r < 4; r++) {
                int rr = rowb + r;
                int b = rr >> 11, s = rr & 2047;
                out[((((size_t)(b * NHEAD + h)) << 11) + s) * HDIM + d] = f2bf(acc[mt][nt][r]);
            }
        }
    }
}

// ---------------- flash attention ----------------
// grid (S/64, H, B), block 256 (4 waves x 16 q-rows). q,k,v bf16 [B,H,S,64].
__global__ __launch_bounds__(256) void flash_kernel(const unsigned short* __restrict__ q,
                                                    const unsigned short* __restrict__ k,
                                                    const unsigned short* __restrict__ v,
                                                    const int* __restrict__ Qlen,
                                                    const int* __restrict__ Vlen,
                                                    float* __restrict__ out) {
    const int b = blockIdx.z, h = blockIdx.y, q0 = blockIdx.x << 6;
    const int tid = threadIdx.x, lane = tid & 63, wave = tid >> 6;
    const int col = lane & 15, grp = lane >> 4;
    const int ql = Qlen[b];
    const int vl = Vlen[b];

    if (q0 >= ql) {  // whole tile is query-masked -> zeros (block-uniform branch)
        int row = q0 + (tid >> 2);
        float* base = out + ((size_t)(b * SEQ + row)) * DM + h * HDIM + (tid & 3) * 16;
        float4 z = {0.f, 0.f, 0.f, 0.f};
        float4* o4 = reinterpret_cast<float4*>(base);
        o4[0] = z; o4[1] = z; o4[2] = z; o4[3] = z;
        return;
    }

    const bool uniform = (vl <= 0);         // fp32 ref collapse: all logits equal -> uniform weights
    const int eff = uniform ? SEQ : vl;     // valid keys: [0, eff)
    const int nkv = (eff + 63) >> 6;

    const size_t hb = ((size_t)(b * NHEAD + h)) << 11;  // *SEQ
    const unsigned short* qbase = q + hb * HDIM;
    const unsigned short* kbase = k + hb * HDIM;
    const unsigned short* vbase = v + hb * HDIM;

    __shared__ unsigned short vT[64 * 80];       // V^T tile [d][key], stride 80 (160B, 16B-aligned)
    __shared__ unsigned short pl[4][16 * 80];    // per-wave P tile [qrow][key]

    // Q fragments (held in registers for all KV tiles)
    const int qrow = q0 + wave * 16 + col;
    bf16x8 aq0 = *reinterpret_cast<const bf16x8*>(&qbase[(size_t)qrow * HDIM + grp * 8]);
    bf16x8 aq1 = *reinterpret_cast<const bf16x8*>(&qbase[(size_t)qrow * HDIM + 32 + grp * 8]);

    f32x4 o_acc[4] = {};
    float m_r[4] = {-3.0e38f, -3.0e38f, -3.0e38f, -3.0e38f};
    float l_r[4] = {0.f, 0.f, 0.f, 0.f};

    for (int kv = 0; kv < nkv; kv++) {
        const int kv0 = kv << 6;

        // ---- stage V^T into LDS (cooperative) ----
        __syncthreads();
        {
            int vrow = tid >> 2;
            int d0 = (tid & 3) * 16;
            bf16x8 v0 = *reinterpret_cast<const bf16x8*>(&vbase[(size_t)(kv0 + vrow) * HDIM + d0]);
            bf16x8 v1 = *reinterpret_cast<const bf16x8*>(&vbase[(size_t)(kv0 + vrow) * HDIM + d0 + 8]);
#pragma unroll
            for (int j = 0; j < 8; j++) {
                vT[(d0 + j) * 80 + vrow]     = (unsigned short)v0[j];
                vT[(d0 + 8 + j) * 80 + vrow] = (unsigned short)v1[j];
            }
        }
        __syncthreads();

        // ---- S = Q K^T  (4 key-col tiles of 16) ----
        f32x4 sf[4] = {};
#pragma unroll
        for (int kc = 0; kc < 4; kc++) {
            int krow = kv0 + kc * 16 + col;
            bf16x8 bk0 = *reinterpret_cast<const bf16x8*>(&kbase[(size_t)krow * HDIM + grp * 8]);
            bf16x8 bk1 = *reinterpret_cast<const bf16x8*>(&kbase[(size_t)krow * HDIM + 32 + grp * 8]);
            sf[kc] = __builtin_amdgcn_mfma_f32_16x16x32_bf16(aq0, bk0, sf[kc], 0, 0, 0);
            sf[kc] = __builtin_amdgcn_mfma_f32_16x16x32_bf16(aq1, bk1, sf[kc], 0, 0, 0);
        }

        // ---- mask ----
#pragma unroll
        for (int kc = 0; kc < 4; kc++) {
            if (uniform) {
                sf[kc][0] = 0.f; sf[kc][1] = 0.f; sf[kc][2] = 0.f; sf[kc][3] = 0.f;
            } else if ((kv0 + kc * 16 + col) >= eff) {
                sf[kc][0] = -1e30f; sf[kc][1] = -1e30f; sf[kc][2] = -1e30f; sf[kc][3] = -1e30f;
            }
        }

        // ---- online softmax (per q-row; 16-lane groups share a row set) ----
#pragma unroll
        for (int r = 0; r < 4; r++) {
            float mx = fmaxf(fmaxf(sf[0][r], sf[1][r]), fmaxf(sf[2][r], sf[3][r]));
            mx = fmaxf(mx, __shfl_xor(mx, 1));
            mx = fmaxf(mx, __shfl_xor(mx, 2));
            mx = fmaxf(mx, __shfl_xor(mx, 4));
            mx = fmaxf(mx, __shfl_xor(mx, 8));
            float mnew = fmaxf(m_r[r], mx);
            float scale = __expf(m_r[r] - mnew);
            float rs = 0.f;
#pragma unroll
            for (int kc = 0; kc < 4; kc++) {
                float p = __expf(sf[kc][r] - mnew);
                sf[kc][r] = p;
                rs += p;
            }
            rs += __shfl_xor(rs, 1);
            rs += __shfl_xor(rs, 2);
            rs += __shfl_xor(rs, 4);
            rs += __shfl_xor(rs, 8);
            l_r[r] = l_r[r] * scale + rs;
            m_r[r] = mnew;
#pragma unroll
            for (int dc = 0; dc < 4; dc++) o_acc[dc][r] *= scale;
        }

        // ---- P -> LDS (bf16), then PV ----
        unsigned short* myp = &pl[wave][0];
#pragma unroll
        for (int kc = 0; kc < 4; kc++)
#pragma unroll
            for (int r = 0; r < 4; r++)
                myp[(grp * 4 + r) * 80 + kc * 16 + col] = f2bf(sf[kc][r]);

#pragma unroll
        for (int ks = 0; ks < 2; ks++) {
            bf16x8 pa = *reinterpret_cast<const bf16x8*>(&myp[col * 80 + ks * 32 + grp * 8]);
#pragma unroll
            for (int dc = 0; dc < 4; dc++) {
                bf16x8 bv = *reinterpret_cast<const bf16x8*>(&vT[(dc * 16 + col) * 80 + ks * 32 + grp * 8]);
                o_acc[dc] = __builtin_amdgcn_mfma_f32_16x16x32_bf16(pa, bv, o_acc[dc], 0, 0, 0);
            }
        }
    }

    // ---- epilogue: O = acc / l, query mask, fp32 out [B,S,H*D] ----
#pragma unroll
    for (int dc = 0; dc < 4; dc++)
#pragma unroll
        for (int r = 0; r < 4; r++) {
            int row = q0 + wave * 16 + grp * 4 + r;
            float val = (row < ql) ? o_acc[dc][r] / l_r[r] : 0.0f;
            out[((size_t)(b * SEQ + row)) * DM + h * HDIM + dc * 16 + col] = val;
        }
}

// ---------------- host launcher ----------------
extern "C" void kernel_launch(void* const* d_in, const int* in_sizes, int n_in,
                              void* d_out, int out_size, void* d_ws, size_t ws_size,
                              hipStream_t stream) {
    const float* Q_seq = (const float*)d_in[0];
    const float* K_seq = (const float*)d_in[1];
    const float* V_seq = (const float*)d_in[2];
    const int* Q_len = (const int*)d_in[3];
    const int* V_len = (const int*)d_in[4];
    const float* WQ = (const float*)d_in[5];
    const float* WK = (const float*)d_in[6];
    const float* WV = (const float*)d_in[7];
    float* out = (float*)d_out;

    // workspace layout (bf16 = ushort): Xbuf[8192*1024], Wt[1024*1024], q/k/v[8192*1024]
    unsigned short* Xbuf = (unsigned short*)d_ws;
    unsigned short* Wt = Xbuf + (size_t)MROWS * DM;
    unsigned short* qb = Wt + (size_t)DM * DM;
    unsigned short* kb = qb + (size_t)MROWS * DM;
    unsigned short* vb = kb + (size_t)MROWS * DM;

    const int n8 = MROWS * DM / 8;  // 1048576
    dim3 cw_grid(DM / 64, DM / 64), cw_blk(64, 4);
    dim3 g_grid(DM / 128, MROWS / 128), g_blk(256);

    // q = (Q_seq @ WQ) / 8   (scale folded into WQ conversion, exact)
    convx_kernel<<<n8 / 256, 256, 0, stream>>>(Q_seq, Xbuf, n8);
    convw_kernel<<<cw_grid, cw_blk, 0, stream>>>(WQ, Wt, 0.125f);
    gemm128_kernel<<<g_grid, g_blk, 0, stream>>>(Xbuf, Wt, qb);
    // k = K_seq @ WK
    convx_kernel<<<n8 / 256, 256, 0, stream>>>(K_seq, Xbuf, n8);
    convw_kernel<<<cw_grid, cw_blk, 0, stream>>>(WK, Wt, 1.0f);
    gemm128_kernel<<<g_grid, g_blk, 0, stream>>>(Xbuf, Wt, kb);
    // v = V_seq @ WV
    convx_kernel<<<n8 / 256, 256, 0, stream>>>(V_seq, Xbuf, n8);
    convw_kernel<<<cw_grid, cw_blk, 0, stream>>>(WV, Wt, 1.0f);
    gemm128_kernel<<<g_grid, g_blk, 0, stream>>>(Xbuf, Wt, vb);

    // attention
    dim3 f_grid(SEQ / 64, NHEAD, BATCH);
    flash_kernel<<<f_grid, 256, 0, stream>>>(qb, kb, vb, Q_len, V_len, out);
}